// Round 12
// baseline (216.589 us; speedup 1.0000x reference)
//
#include <hip/hip_runtime.h>
#include <hip/hip_bf16.h>
#include <stdint.h>

typedef __bf16 bf16;
typedef __bf16 bf16x4 __attribute__((ext_vector_type(4)));
typedef __bf16 bf16x8 __attribute__((ext_vector_type(8)));
typedef float f32x4 __attribute__((ext_vector_type(4)));
typedef float f32x16 __attribute__((ext_vector_type(16)));

#define D_MODEL 768
#define NUM_HEADS 48
#define HEAD_CH 16
#define INNER 2304
#define BATCH 2
#define SEQLEN 2048
#define M_ROWS (BATCH * SEQLEN)
#define EPSF 1e-6f
#define SST 36  // S-tile stride (bf16): 2-way LDS bank alias (free), 8B-aligned

// async global->LDS, 16B per lane. LDS dest must be wave-uniform base + lane*16.
__device__ inline void gload_lds16(const void* g, void* l) {
  __builtin_amdgcn_global_load_lds((__attribute__((address_space(1))) void*)(g),
                                   (__attribute__((address_space(3))) void*)(l),
                                   16, 0, 0);
}

// ---------------------------------------------------------------------------
// fused dual f32 -> bf16 convert (two independent tensors, one launch)
// ---------------------------------------------------------------------------
__global__ __launch_bounds__(256) void cvt2_f32_bf16(
    const float* __restrict__ a, bf16* __restrict__ da, int na4,
    const float* __restrict__ b, bf16* __restrict__ db, int nb4) {
  int j = blockIdx.x * 256 + threadIdx.x;
  const float* s;
  bf16* d;
  if (j < na4) {
    s = a; d = da;
  } else {
    j -= na4;
    if (j >= nb4) return;
    s = b; d = db;
  }
  const float4 v = ((const float4*)s)[j];
  bf16x4 o;
  o[0] = (bf16)v.x; o[1] = (bf16)v.y; o[2] = (bf16)v.z; o[3] = (bf16)v.w;
  ((bf16x4*)d)[j] = o;
}

__global__ __launch_bounds__(256) void cvt_f32_bf16(
    const float* __restrict__ src, bf16* __restrict__ dst, int n4) {
  const int i = blockIdx.x * 256 + threadIdx.x;
  if (i < n4) {
    const float4 v = ((const float4*)src)[i];
    bf16x4 o;
    o[0] = (bf16)v.x; o[1] = (bf16)v.y; o[2] = (bf16)v.z; o[3] = (bf16)v.w;
    ((bf16x4*)dst)[i] = o;
  }
}

// ---------------------------------------------------------------------------
// GEMM: C[m,n] = sum_k A[m,k]*W[n,k] + bias[n] (+ skip[m,n]); A (M,K), W (N,K)
// m97 pattern, TM x TN tile, BK=32, 4 waves in 2x2; global_load_lds x16.
// ---------------------------------------------------------------------------
template <int TM, int TN, int NCOLS, bool ADD_SKIP, typename CT>
__global__ __launch_bounds__(256) void gemm_bt(
    const bf16* __restrict__ A, const bf16* __restrict__ W,
    const float* __restrict__ bias, const float* __restrict__ skip,
    CT* __restrict__ C, int K) {
  constexpr int MI = TM / 32;  // m-frags per wave
  constexpr int NI = TN / 32;  // n-frags per wave
  __shared__ __align__(16) bf16 As[TM * 32];
  __shared__ __align__(16) bf16 Bs[TN * 32];
  const int t = threadIdx.x;
  const int lane = t & 63, w = t >> 6;
  const int wm = (w >> 1) * (TM / 2), wn = (w & 1) * (TN / 2);
  const int row16 = lane & 15, quad = lane >> 4;
  const int m0 = blockIdx.x * TM, n0 = blockIdx.y * TN;

  f32x4 zero4 = {0.f, 0.f, 0.f, 0.f};
  f32x4 acc[MI][NI];
#pragma unroll
  for (int mi = 0; mi < MI; ++mi)
#pragma unroll
    for (int ni = 0; ni < NI; ++ni) acc[mi][ni] = zero4;

  const int arow = t >> 2;
  const int acol = (t & 3) * 8;
  const bf16* Ab = A + (size_t)m0 * K;
  const bf16* Wb = W + (size_t)n0 * K;

  for (int kt = 0; kt < K; kt += 32) {
    gload_lds16(Ab + (size_t)arow * K + kt + acol, As + t * 8);
    if (TM == 128)
      gload_lds16(Ab + (size_t)(64 + arow) * K + kt + acol, As + 2048 + t * 8);
    gload_lds16(Wb + (size_t)arow * K + kt + acol, Bs + t * 8);
    if (TN == 128)
      gload_lds16(Wb + (size_t)(64 + arow) * K + kt + acol, Bs + 2048 + t * 8);
    __syncthreads();

    bf16x8 af[MI], wf[NI];
#pragma unroll
    for (int mi = 0; mi < MI; ++mi)
      af[mi] = *(const bf16x8*)&As[(wm + mi * 16 + row16) * 32 + quad * 8];
#pragma unroll
    for (int ni = 0; ni < NI; ++ni)
      wf[ni] = *(const bf16x8*)&Bs[(wn + ni * 16 + row16) * 32 + quad * 8];
#pragma unroll
    for (int mi = 0; mi < MI; ++mi)
#pragma unroll
      for (int ni = 0; ni < NI; ++ni)
        acc[mi][ni] = __builtin_amdgcn_mfma_f32_16x16x32_bf16(
            af[mi], wf[ni], acc[mi][ni], 0, 0, 0);
    __syncthreads();
  }

#pragma unroll
  for (int mi = 0; mi < MI; ++mi) {
#pragma unroll
    for (int ni = 0; ni < NI; ++ni) {
      const int col = n0 + wn + ni * 16 + row16;
      const float bv = bias[col];
#pragma unroll
      for (int r = 0; r < 4; ++r) {
        const int row = m0 + wm + mi * 16 + quad * 4 + r;
        float v = acc[mi][ni][r] + bv;
        if (ADD_SKIP) v += skip[(size_t)row * NCOLS + col];
        C[(size_t)row * NCOLS + col] = (CT)v;
      }
    }
  }
}

// ---------------------------------------------------------------------------
// Q+K+V causal width-3 conv from u:
//   ch 0..15  -> Q (B,N,L,16);  16..31 -> K (B,N,L,16);  32..47 -> V (B,N,16,L)
// ---------------------------------------------------------------------------
__global__ __launch_bounds__(256) void conv_qkv(
    const bf16* __restrict__ u, const float* __restrict__ w_sf,
    const float* __restrict__ b_sf, bf16* __restrict__ qq,
    bf16* __restrict__ kk, bf16* __restrict__ vv) {
  const int nh = blockIdx.x, b = blockIdx.y, lc = blockIdx.z;
  const int l0 = lc * 128;
  __shared__ __align__(8) bf16 ut[130 * 48];
  const int t = threadIdx.x;
  for (int i = t; i < 130 * 12; i += 256) {
    const int lr = i / 12, qd = i % 12;
    const int l = l0 - 2 + lr;
    uint2 val;
    val.x = 0u; val.y = 0u;
    if (l >= 0)
      val = *(const uint2*)&u[(size_t)(b * SEQLEN + l) * INNER + nh * 48 + qd * 4];
    *(uint2*)&ut[lr * 48 + qd * 4] = val;
  }
  __syncthreads();
  const size_t bn = (size_t)(b * NUM_HEADS + nh);
#pragma unroll
  for (int s = 0; s < 2; ++s) {
    bf16* dst = (s == 0) ? qq : kk;
    const int cb = s * 16;
    for (int i = t; i < 128 * 16; i += 256) {
      const int c = i & 15, lr = i >> 4;
      const int e = nh * 48 + cb + c;
      const float val = w_sf[e * 3 + 0] * (float)ut[lr * 48 + cb + c] +
                        w_sf[e * 3 + 1] * (float)ut[(lr + 1) * 48 + cb + c] +
                        w_sf[e * 3 + 2] * (float)ut[(lr + 2) * 48 + cb + c] +
                        b_sf[e];
      dst[(bn * SEQLEN + l0 + lr) * 16 + c] = (bf16)val;
    }
  }
  for (int i = t; i < 128 * 16; i += 256) {
    const int lr = i & 127, c = i >> 7;
    const int e = nh * 48 + 32 + c;
    const float val = w_sf[e * 3 + 0] * (float)ut[lr * 48 + 32 + c] +
                      w_sf[e * 3 + 1] * (float)ut[(lr + 1) * 48 + 32 + c] +
                      w_sf[e * 3 + 2] * (float)ut[(lr + 2) * 48 + 32 + c] +
                      b_sf[e];
    vv[(bn * 16 + c) * SEQLEN + l0 + lr] = (bf16)val;
  }
}

// ---------------------------------------------------------------------------
// Causal h-weighted attention v9 = r10 structure (best: 47.96us) + bf16 y +
// S-tile stride 36 (2-way bank alias = free, vs 4-way at stride 40).
// One 32-row Q tile/block, KV split 4 ways across waves (6144 blocks,
// z-reversed big-first). S^T = mfma_32x32x16(K,Q); zero-padded LDS h table;
// S->A via LDS round-trip; PV = 2x mfma_16x16x32; cross-wave O reduce in LDS.
// ---------------------------------------------------------------------------
__global__ __launch_bounds__(256) void attn_kernel(
    const bf16* __restrict__ qq, const bf16* __restrict__ kk,
    const bf16* __restrict__ vv, const float* __restrict__ hg,
    bf16* __restrict__ y) {
  const int nh = blockIdx.x, b = blockIdx.y;
  const int q32 = (int)gridDim.z - 1 - (int)blockIdx.z;  // big tiles first
  const int l0 = q32 * 32;
  __shared__ __align__(16) float hs[32 + SEQLEN];  // hs[32+d]=h[d], pad=0
  __shared__ __align__(16) bf16 st[4 * 32 * SST];  // per-wave S-tile / O-redux
  const int t = threadIdx.x;
  // fill hs[0 .. l0+64): 8 zero-float4s then h[0 .. l0+32)
  const int n4 = (l0 + 64) >> 2;
  for (int i = t; i < n4; i += 256) {
    float4 val = {0.f, 0.f, 0.f, 0.f};
    if (i >= 8) val = ((const float4*)(hg + nh * SEQLEN))[i - 8];
    ((float4*)hs)[i] = val;
  }
  __syncthreads();

  const int w = t >> 6, lane = t & 63;
  const int l31 = lane & 31, hi = lane >> 5;
  const int row16 = lane & 15, quad = lane >> 4;
  const size_t bn = (size_t)(b * NUM_HEADS + nh);
  const bf16* qb = qq + bn * SEQLEN * 16;
  const bf16* kb = kk + bn * SEQLEN * 16;
  const bf16* vb = vv + bn * 16 * SEQLEN;

  bf16x8 zf;
#pragma unroll
  for (int j = 0; j < 8; ++j) zf[j] = (bf16)0.f;
  const f32x4 zacc4 = {0.f, 0.f, 0.f, 0.f};
  f32x16 zacc16;
#pragma unroll
  for (int j = 0; j < 16; ++j) zacc16[j] = 0.f;

  // Q B-operand frag: lane l31 holds Q[l0+l31][ch hi*8..+8]
  const bf16x8 qf = *(const bf16x8*)&qb[(l0 + l31) * 16 + hi * 8];

  f32x4 o0 = zacc4, o1 = zacc4;
  bf16* sw = &st[w * 32 * SST];

  int mc = w * 32;
  bf16x8 kf = zf, vf = zf;
  if (mc <= l0) {
    kf = *(const bf16x8*)&kb[(mc + l31) * 16 + hi * 8];
    vf = *(const bf16x8*)&vb[row16 * SEQLEN + mc + quad * 8];
  }
  for (; mc <= l0; mc += 128) {
    const int mn = mc + 128;
    bf16x8 kf2 = zf, vf2 = zf;
    if (mn <= l0) {  // prefetch next chunk
      kf2 = *(const bf16x8*)&kb[(mn + l31) * 16 + hi * 8];
      vf2 = *(const bf16x8*)&vb[row16 * SEQLEN + mn + quad * 8];
    }
    // S^T[m-local=rows][l-local=cols] = sum_ch K*Q
    f32x16 s = __builtin_amdgcn_mfma_f32_32x32x16_bf16(kf, qf, zacc16, 0, 0, 0);

    // h-weight; causal mask free via zero pad. reg j -> hp[3-j]
    const int d0 = 32 + (l0 - mc) + l31 - 4 * hi;
#pragma unroll
    for (int g = 0; g < 4; ++g) {
      const float* hp = &hs[d0 - 8 * g - 3];
      bf16x4 pk;
      pk[0] = (bf16)(s[4 * g + 0] * hp[3]);
      pk[1] = (bf16)(s[4 * g + 1] * hp[2]);
      pk[2] = (bf16)(s[4 * g + 2] * hp[1]);
      pk[3] = (bf16)(s[4 * g + 3] * hp[0]);
      *(bf16x4*)&sw[l31 * SST + 8 * g + 4 * hi] = pk;
    }
    asm volatile("s_waitcnt lgkmcnt(0)" ::: "memory");  // stores before reads
    // PV: A = S[l][m] (b128), B = V[m][j] frag (shared by both halves)
    const bf16x8 sf0 = *(const bf16x8*)&sw[row16 * SST + quad * 8];
    const bf16x8 sf1 = *(const bf16x8*)&sw[(row16 + 16) * SST + quad * 8];
    o0 = __builtin_amdgcn_mfma_f32_16x16x32_bf16(sf0, vf, o0, 0, 0, 0);
    o1 = __builtin_amdgcn_mfma_f32_16x16x32_bf16(sf1, vf, o1, 0, 0, 0);
    asm volatile("" ::: "memory");  // reads before next-iter stores
    kf = kf2; vf = vf2;
  }

  // per-wave O into own LDS region (f32 32x16 = 2048B < 32*SST*2B), reduce
  float* ob = (float*)&st[w * 32 * SST];
#pragma unroll
  for (int r = 0; r < 4; ++r) {
    ob[(quad * 4 + r) * 16 + row16] = o0[r];
    ob[(quad * 4 + r + 16) * 16 + row16] = o1[r];
  }
  __syncthreads();
  for (int i = t; i < 32 * 16; i += 256) {
    const int l = i >> 4, j = i & 15;
    float sum = 0.f;
#pragma unroll
    for (int ww = 0; ww < 4; ++ww)
      sum += ((const float*)&st[ww * 32 * SST])[l * 16 + j];
    y[((size_t)(b * SEQLEN + l0 + l) * NUM_HEADS + nh) * 16 + j] = (bf16)sum;
  }
}

// ---------------------------------------------------------------------------
// RMSNorm over D=768 per row: y bf16 in, yn bf16 out, * norm_w (f32)
// ---------------------------------------------------------------------------
__global__ __launch_bounds__(256) void rmsnorm_k(
    const bf16* __restrict__ y, const float* __restrict__ nw,
    bf16* __restrict__ yn) {
  const int row = blockIdx.x;
  const int t = threadIdx.x;
  const bf16* yr = y + (size_t)row * D_MODEL;
  const float v0 = (float)yr[t];
  const float v1 = (float)yr[t + 256];
  const float v2 = (float)yr[t + 512];
  float ss = v0 * v0 + v1 * v1 + v2 * v2;
#pragma unroll
  for (int off = 32; off >= 1; off >>= 1) ss += __shfl_down(ss, off, 64);
  __shared__ float red[4];
  if ((t & 63) == 0) red[t >> 6] = ss;
  __syncthreads();
  const float tot = red[0] + red[1] + red[2] + red[3];
  const float r = rsqrtf(tot * (1.f / 768.f) + EPSF);
  bf16* yo = yn + (size_t)row * D_MODEL;
  yo[t] = (bf16)(v0 * r * nw[t]);
  yo[t + 256] = (bf16)(v1 * r * nw[t + 256]);
  yo[t + 512] = (bf16)(v2 * r * nw[t + 512]);
}

// ---------------------------------------------------------------------------
extern "C" void kernel_launch(void* const* d_in, const int* in_sizes, int n_in,
                              void* d_out, int out_size, void* d_ws,
                              size_t ws_size, hipStream_t stream) {
  const float* inputs = (const float*)d_in[0];
  const float* w_in = (const float*)d_in[1];
  const float* b_in = (const float*)d_in[2];
  const float* w_sf = (const float*)d_in[3];
  const float* b_sf = (const float*)d_in[4];
  const float* hb = (const float*)d_in[5];
  const float* norm_w = (const float*)d_in[6];
  const float* w_out = (const float*)d_in[7];
  const float* b_out = (const float*)d_in[8];

  // ws plan (37.8 MB), region lifetimes:
  //   u   18.9 MB : GEMM1 out -> dead after conv_qkv; tail reused for
  //                 wout16 (+0, 1.2MB), yn (+2MB, 6.3MB), y16 (+9MB, 6.3MB)
  //   v    6.3 MB : V
  //   A    6.3 MB : in16 (GEMM1 A) -> k16 (attn) -> dead
  //   B    6.3 MB : win16 (GEMM1 W, 3.5MB) -> q16 (attn)
  char* ws = (char*)d_ws;
  const size_t U_B = (size_t)M_ROWS * INNER * 2;
  const size_t V_B = (size_t)BATCH * NUM_HEADS * HEAD_CH * SEQLEN * 2;
  const size_t SLOT_B = (size_t)M_ROWS * D_MODEL * 2;
  bf16* u = (bf16*)(ws);
  bf16* wout16 = (bf16*)(ws);                    // u region, after conv
  bf16* yn = (bf16*)(ws + (2 << 20));            // u region +2MB
  bf16* y16 = (bf16*)(ws + (9 << 20));           // u region +9MB
  bf16* v = (bf16*)(ws + U_B);
  bf16* in16 = (bf16*)(ws + U_B + V_B);          // A
  bf16* k16 = in16;                              // A after GEMM1
  bf16* win16 = (bf16*)(ws + U_B + V_B + SLOT_B);// B
  bf16* q16 = win16;                             // B after GEMM1
  float* out = (float*)d_out;

  const int n4_in = M_ROWS * D_MODEL / 4;
  const int n4_win = INNER * D_MODEL / 4;
  const int n4_wout = D_MODEL * D_MODEL / 4;
  hipLaunchKernelGGL(cvt2_f32_bf16, dim3((n4_in + n4_win + 255) / 256),
                     dim3(256), 0, stream, inputs, in16, n4_in, w_in, win16,
                     n4_win);

  hipLaunchKernelGGL((gemm_bt<64, 128, INNER, false, bf16>), dim3(64, 18),
                     dim3(256), 0, stream, in16, win16, b_in,
                     (const float*)nullptr, u, 768);
  hipLaunchKernelGGL(conv_qkv, dim3(48, 2, 16), dim3(256), 0, stream, u, w_sf,
                     b_sf, q16, k16, v);
  // u dead now: stage w_out into its head
  hipLaunchKernelGGL(cvt_f32_bf16, dim3((n4_wout + 255) / 256), dim3(256), 0,
                     stream, w_out, wout16, n4_wout);
  hipLaunchKernelGGL(attn_kernel, dim3(48, 2, 64), dim3(256), 0, stream, q16,
                     k16, v, hb, y16);
  hipLaunchKernelGGL(rmsnorm_k, dim3(M_ROWS), dim3(256), 0, stream, y16,
                     norm_w, yn);
  hipLaunchKernelGGL((gemm_bt<64, 64, D_MODEL, true, float>), dim3(64, 12),
                     dim3(256), 0, stream, yn, wout16, b_out, inputs, out,
                     768);
}

// Round 13
// 189.749 us; speedup vs baseline: 1.1414x; 1.1414x over previous
//
#include <hip/hip_runtime.h>
#include <hip/hip_bf16.h>
#include <stdint.h>

typedef __bf16 bf16;
typedef __bf16 bf16x4 __attribute__((ext_vector_type(4)));
typedef __bf16 bf16x8 __attribute__((ext_vector_type(8)));
typedef float f32x4 __attribute__((ext_vector_type(4)));
typedef float f32x16 __attribute__((ext_vector_type(16)));

#define D_MODEL 768
#define NUM_HEADS 48
#define HEAD_CH 16
#define INNER 2304
#define BATCH 2
#define SEQLEN 2048
#define M_ROWS (BATCH * SEQLEN)
#define EPSF 1e-6f
// S-tile stride (bf16). MUST be 0 mod 8 (16B row alignment for ds_read_b128 —
// stride 36 broke this and cost +27us in r12). 40 = best aligned choice.
#define SST 40

// async global->LDS, 16B per lane. LDS dest must be wave-uniform base + lane*16.
__device__ inline void gload_lds16(const void* g, void* l) {
  __builtin_amdgcn_global_load_lds((__attribute__((address_space(1))) void*)(g),
                                   (__attribute__((address_space(3))) void*)(l),
                                   16, 0, 0);
}

// ---------------------------------------------------------------------------
// fused dual f32 -> bf16 convert (two independent tensors, one launch)
// ---------------------------------------------------------------------------
__global__ __launch_bounds__(256) void cvt2_f32_bf16(
    const float* __restrict__ a, bf16* __restrict__ da, int na4,
    const float* __restrict__ b, bf16* __restrict__ db, int nb4) {
  int j = blockIdx.x * 256 + threadIdx.x;
  const float* s;
  bf16* d;
  if (j < na4) {
    s = a; d = da;
  } else {
    j -= na4;
    if (j >= nb4) return;
    s = b; d = db;
  }
  const float4 v = ((const float4*)s)[j];
  bf16x4 o;
  o[0] = (bf16)v.x; o[1] = (bf16)v.y; o[2] = (bf16)v.z; o[3] = (bf16)v.w;
  ((bf16x4*)d)[j] = o;
}

__global__ __launch_bounds__(256) void cvt_f32_bf16(
    const float* __restrict__ src, bf16* __restrict__ dst, int n4) {
  const int i = blockIdx.x * 256 + threadIdx.x;
  if (i < n4) {
    const float4 v = ((const float4*)src)[i];
    bf16x4 o;
    o[0] = (bf16)v.x; o[1] = (bf16)v.y; o[2] = (bf16)v.z; o[3] = (bf16)v.w;
    ((bf16x4*)dst)[i] = o;
  }
}

// ---------------------------------------------------------------------------
// GEMM: C[m,n] = sum_k A[m,k]*W[n,k] + bias[n] (+ skip[m,n]); A (M,K), W (N,K)
// m97 pattern, TM x TN tile, BK=32, 4 waves in 2x2; global_load_lds x16.
// ---------------------------------------------------------------------------
template <int TM, int TN, int NCOLS, bool ADD_SKIP, typename CT>
__global__ __launch_bounds__(256) void gemm_bt(
    const bf16* __restrict__ A, const bf16* __restrict__ W,
    const float* __restrict__ bias, const float* __restrict__ skip,
    CT* __restrict__ C, int K) {
  constexpr int MI = TM / 32;  // m-frags per wave
  constexpr int NI = TN / 32;  // n-frags per wave
  __shared__ __align__(16) bf16 As[TM * 32];
  __shared__ __align__(16) bf16 Bs[TN * 32];
  const int t = threadIdx.x;
  const int lane = t & 63, w = t >> 6;
  const int wm = (w >> 1) * (TM / 2), wn = (w & 1) * (TN / 2);
  const int row16 = lane & 15, quad = lane >> 4;
  const int m0 = blockIdx.x * TM, n0 = blockIdx.y * TN;

  f32x4 zero4 = {0.f, 0.f, 0.f, 0.f};
  f32x4 acc[MI][NI];
#pragma unroll
  for (int mi = 0; mi < MI; ++mi)
#pragma unroll
    for (int ni = 0; ni < NI; ++ni) acc[mi][ni] = zero4;

  const int arow = t >> 2;
  const int acol = (t & 3) * 8;
  const bf16* Ab = A + (size_t)m0 * K;
  const bf16* Wb = W + (size_t)n0 * K;

  for (int kt = 0; kt < K; kt += 32) {
    gload_lds16(Ab + (size_t)arow * K + kt + acol, As + t * 8);
    if (TM == 128)
      gload_lds16(Ab + (size_t)(64 + arow) * K + kt + acol, As + 2048 + t * 8);
    gload_lds16(Wb + (size_t)arow * K + kt + acol, Bs + t * 8);
    if (TN == 128)
      gload_lds16(Wb + (size_t)(64 + arow) * K + kt + acol, Bs + 2048 + t * 8);
    __syncthreads();

    bf16x8 af[MI], wf[NI];
#pragma unroll
    for (int mi = 0; mi < MI; ++mi)
      af[mi] = *(const bf16x8*)&As[(wm + mi * 16 + row16) * 32 + quad * 8];
#pragma unroll
    for (int ni = 0; ni < NI; ++ni)
      wf[ni] = *(const bf16x8*)&Bs[(wn + ni * 16 + row16) * 32 + quad * 8];
#pragma unroll
    for (int mi = 0; mi < MI; ++mi)
#pragma unroll
      for (int ni = 0; ni < NI; ++ni)
        acc[mi][ni] = __builtin_amdgcn_mfma_f32_16x16x32_bf16(
            af[mi], wf[ni], acc[mi][ni], 0, 0, 0);
    __syncthreads();
  }

#pragma unroll
  for (int mi = 0; mi < MI; ++mi) {
#pragma unroll
    for (int ni = 0; ni < NI; ++ni) {
      const int col = n0 + wn + ni * 16 + row16;
      const float bv = bias[col];
#pragma unroll
      for (int r = 0; r < 4; ++r) {
        const int row = m0 + wm + mi * 16 + quad * 4 + r;
        float v = acc[mi][ni][r] + bv;
        if (ADD_SKIP) v += skip[(size_t)row * NCOLS + col];
        C[(size_t)row * NCOLS + col] = (CT)v;
      }
    }
  }
}

// ---------------------------------------------------------------------------
// Q+K+V causal width-3 conv from u:
//   ch 0..15  -> Q (B,N,L,16);  16..31 -> K (B,N,L,16);  32..47 -> V (B,N,16,L)
// ---------------------------------------------------------------------------
__global__ __launch_bounds__(256) void conv_qkv(
    const bf16* __restrict__ u, const float* __restrict__ w_sf,
    const float* __restrict__ b_sf, bf16* __restrict__ qq,
    bf16* __restrict__ kk, bf16* __restrict__ vv) {
  const int nh = blockIdx.x, b = blockIdx.y, lc = blockIdx.z;
  const int l0 = lc * 128;
  __shared__ __align__(8) bf16 ut[130 * 48];
  const int t = threadIdx.x;
  for (int i = t; i < 130 * 12; i += 256) {
    const int lr = i / 12, qd = i % 12;
    const int l = l0 - 2 + lr;
    uint2 val;
    val.x = 0u; val.y = 0u;
    if (l >= 0)
      val = *(const uint2*)&u[(size_t)(b * SEQLEN + l) * INNER + nh * 48 + qd * 4];
    *(uint2*)&ut[lr * 48 + qd * 4] = val;
  }
  __syncthreads();
  const size_t bn = (size_t)(b * NUM_HEADS + nh);
#pragma unroll
  for (int s = 0; s < 2; ++s) {
    bf16* dst = (s == 0) ? qq : kk;
    const int cb = s * 16;
    for (int i = t; i < 128 * 16; i += 256) {
      const int c = i & 15, lr = i >> 4;
      const int e = nh * 48 + cb + c;
      const float val = w_sf[e * 3 + 0] * (float)ut[lr * 48 + cb + c] +
                        w_sf[e * 3 + 1] * (float)ut[(lr + 1) * 48 + cb + c] +
                        w_sf[e * 3 + 2] * (float)ut[(lr + 2) * 48 + cb + c] +
                        b_sf[e];
      dst[(bn * SEQLEN + l0 + lr) * 16 + c] = (bf16)val;
    }
  }
  for (int i = t; i < 128 * 16; i += 256) {
    const int lr = i & 127, c = i >> 7;
    const int e = nh * 48 + 32 + c;
    const float val = w_sf[e * 3 + 0] * (float)ut[lr * 48 + 32 + c] +
                      w_sf[e * 3 + 1] * (float)ut[(lr + 1) * 48 + 32 + c] +
                      w_sf[e * 3 + 2] * (float)ut[(lr + 2) * 48 + 32 + c] +
                      b_sf[e];
    vv[(bn * 16 + c) * SEQLEN + l0 + lr] = (bf16)val;
  }
}

// ---------------------------------------------------------------------------
// Causal h-weighted attention v10: r10 inner loop (stride 40, proven) +
// BALANCED paired tiles: block z owns tiles (z, 63-z); combined KV chunks =
// 65 for every z; the 65 steps are dealt round-robin to the 4 waves (wave w
// takes steps s==w mod 4 -> two stride-128 loops starting at w*32 / j0*32).
// Every wave of every block does 16-17 steps -> uniform duration. 3072 blocks.
// Epilogue reduces tile A then tile B, reusing the per-wave S-tile LDS.
// ---------------------------------------------------------------------------
__global__ __launch_bounds__(256) void attn_kernel(
    const bf16* __restrict__ qq, const bf16* __restrict__ kk,
    const bf16* __restrict__ vv, const float* __restrict__ hg,
    bf16* __restrict__ y) {
  const int nh = blockIdx.x, b = blockIdx.y;
  const int qa = blockIdx.z, qb = 63 - qa;  // paired tiles
  const int l0a = qa * 32, l0b = qb * 32;
  __shared__ __align__(16) float hs[32 + SEQLEN];  // hs[32+d]=h[d], pad=0
  __shared__ __align__(16) bf16 st[4 * 32 * SST];  // per-wave S-tile / O-redux
  const int t = threadIdx.x;
  // fill hs[0 .. l0b+64): 8 zero-float4s then h[0 .. l0b+32)
  const int n4 = (l0b + 64) >> 2;
  for (int i = t; i < n4; i += 256) {
    float4 val = {0.f, 0.f, 0.f, 0.f};
    if (i >= 8) val = ((const float4*)(hg + nh * SEQLEN))[i - 8];
    ((float4*)hs)[i] = val;
  }
  __syncthreads();

  const int w = t >> 6, lane = t & 63;
  const int l31 = lane & 31, hi = lane >> 5;
  const int row16 = lane & 15, quad = lane >> 4;
  const size_t bn = (size_t)(b * NUM_HEADS + nh);
  const bf16* qp = qq + bn * SEQLEN * 16;
  const bf16* kb = kk + bn * SEQLEN * 16;
  const bf16* vb = vv + bn * 16 * SEQLEN;

  bf16x8 zf;
#pragma unroll
  for (int j = 0; j < 8; ++j) zf[j] = (bf16)0.f;
  const f32x4 zacc4 = {0.f, 0.f, 0.f, 0.f};
  f32x16 zacc16;
#pragma unroll
  for (int j = 0; j < 16; ++j) zacc16[j] = 0.f;

  // Q frags for both tiles
  const bf16x8 qfa = *(const bf16x8*)&qp[(l0a + l31) * 16 + hi * 8];
  const bf16x8 qfb = *(const bf16x8*)&qp[(l0b + l31) * 16 + hi * 8];

  bf16* sw = &st[w * 32 * SST];

  auto run_pass = [&](const bf16x8& qf, const int l0, const int mc0,
                      f32x4& o0, f32x4& o1) {
    int mc = mc0;
    bf16x8 kf = zf, vf = zf;
    if (mc <= l0) {
      kf = *(const bf16x8*)&kb[(mc + l31) * 16 + hi * 8];
      vf = *(const bf16x8*)&vb[row16 * SEQLEN + mc + quad * 8];
    }
    for (; mc <= l0; mc += 128) {
      const int mn = mc + 128;
      bf16x8 kf2 = zf, vf2 = zf;
      if (mn <= l0) {  // prefetch next chunk
        kf2 = *(const bf16x8*)&kb[(mn + l31) * 16 + hi * 8];
        vf2 = *(const bf16x8*)&vb[row16 * SEQLEN + mn + quad * 8];
      }
      // S^T[m-local=rows][l-local=cols] = sum_ch K*Q
      f32x16 s =
          __builtin_amdgcn_mfma_f32_32x32x16_bf16(kf, qf, zacc16, 0, 0, 0);

      // h-weight; causal mask free via zero pad. reg j -> hp[3-j]
      const int d0 = 32 + (l0 - mc) + l31 - 4 * hi;
#pragma unroll
      for (int g = 0; g < 4; ++g) {
        const float* hp = &hs[d0 - 8 * g - 3];
        bf16x4 pk;
        pk[0] = (bf16)(s[4 * g + 0] * hp[3]);
        pk[1] = (bf16)(s[4 * g + 1] * hp[2]);
        pk[2] = (bf16)(s[4 * g + 2] * hp[1]);
        pk[3] = (bf16)(s[4 * g + 3] * hp[0]);
        *(bf16x4*)&sw[l31 * SST + 8 * g + 4 * hi] = pk;
      }
      asm volatile("s_waitcnt lgkmcnt(0)" ::: "memory");  // stores -> reads
      // PV: A = S[l][m] (b128), B = V[m][j] frag (shared by both halves)
      const bf16x8 sf0 = *(const bf16x8*)&sw[row16 * SST + quad * 8];
      const bf16x8 sf1 = *(const bf16x8*)&sw[(row16 + 16) * SST + quad * 8];
      o0 = __builtin_amdgcn_mfma_f32_16x16x32_bf16(sf0, vf, o0, 0, 0, 0);
      o1 = __builtin_amdgcn_mfma_f32_16x16x32_bf16(sf1, vf, o1, 0, 0, 0);
      asm volatile("" ::: "memory");  // reads before next-iter stores
      kf = kf2; vf = vf2;
    }
  };

  f32x4 o0a = zacc4, o1a = zacc4, o0b = zacc4, o1b = zacc4;
  // tile A: steps s = w, w+4, ... in [0, qa]  -> chunks w*32 stride 128
  run_pass(qfa, l0a, w * 32, o0a, o1a);
  // tile B: steps s > qa with s == w (mod 4) -> chunk j = s-qa-1 from j0
  const int j0 = ((w - qa - 1) % 4 + 4) % 4;
  run_pass(qfb, l0b, j0 * 32, o0b, o1b);

  // epilogue: two phases reusing st as 4 x (32x16 f32) reduction buffers
  float* ob = (float*)&st[w * 32 * SST];
#pragma unroll
  for (int phase = 0; phase < 2; ++phase) {
    const f32x4& p0 = phase ? o0b : o0a;
    const f32x4& p1 = phase ? o1b : o1a;
    const int lt = phase ? l0b : l0a;
    __syncthreads();  // prior phase reads (or hs use) done before overwrite
#pragma unroll
    for (int r = 0; r < 4; ++r) {
      ob[(quad * 4 + r) * 16 + row16] = p0[r];
      ob[(quad * 4 + r + 16) * 16 + row16] = p1[r];
    }
    __syncthreads();
    for (int i = t; i < 32 * 16; i += 256) {
      const int l = i >> 4, j = i & 15;
      float sum = 0.f;
#pragma unroll
      for (int ww = 0; ww < 4; ++ww)
        sum += ((const float*)&st[ww * 32 * SST])[l * 16 + j];
      y[((size_t)(b * SEQLEN + lt + l) * NUM_HEADS + nh) * 16 + j] = (bf16)sum;
    }
  }
}

// ---------------------------------------------------------------------------
// RMSNorm over D=768 per row: y bf16 in, yn bf16 out, * norm_w (f32)
// ---------------------------------------------------------------------------
__global__ __launch_bounds__(256) void rmsnorm_k(
    const bf16* __restrict__ y, const float* __restrict__ nw,
    bf16* __restrict__ yn) {
  const int row = blockIdx.x;
  const int t = threadIdx.x;
  const bf16* yr = y + (size_t)row * D_MODEL;
  const float v0 = (float)yr[t];
  const float v1 = (float)yr[t + 256];
  const float v2 = (float)yr[t + 512];
  float ss = v0 * v0 + v1 * v1 + v2 * v2;
#pragma unroll
  for (int off = 32; off >= 1; off >>= 1) ss += __shfl_down(ss, off, 64);
  __shared__ float red[4];
  if ((t & 63) == 0) red[t >> 6] = ss;
  __syncthreads();
  const float tot = red[0] + red[1] + red[2] + red[3];
  const float r = rsqrtf(tot * (1.f / 768.f) + EPSF);
  bf16* yo = yn + (size_t)row * D_MODEL;
  yo[t] = (bf16)(v0 * r * nw[t]);
  yo[t + 256] = (bf16)(v1 * r * nw[t + 256]);
  yo[t + 512] = (bf16)(v2 * r * nw[t + 512]);
}

// ---------------------------------------------------------------------------
extern "C" void kernel_launch(void* const* d_in, const int* in_sizes, int n_in,
                              void* d_out, int out_size, void* d_ws,
                              size_t ws_size, hipStream_t stream) {
  const float* inputs = (const float*)d_in[0];
  const float* w_in = (const float*)d_in[1];
  const float* b_in = (const float*)d_in[2];
  const float* w_sf = (const float*)d_in[3];
  const float* b_sf = (const float*)d_in[4];
  const float* hb = (const float*)d_in[5];
  const float* norm_w = (const float*)d_in[6];
  const float* w_out = (const float*)d_in[7];
  const float* b_out = (const float*)d_in[8];

  // ws plan (37.8 MB), region lifetimes:
  //   u   18.9 MB : GEMM1 out -> dead after conv_qkv; tail reused for
  //                 wout16 (+0, 1.2MB), yn (+2MB, 6.3MB), y16 (+9MB, 6.3MB)
  //   v    6.3 MB : V
  //   A    6.3 MB : in16 (GEMM1 A) -> k16 (attn) -> dead
  //   B    6.3 MB : win16 (GEMM1 W, 3.5MB) -> q16 (attn)
  char* ws = (char*)d_ws;
  const size_t U_B = (size_t)M_ROWS * INNER * 2;
  const size_t V_B = (size_t)BATCH * NUM_HEADS * HEAD_CH * SEQLEN * 2;
  const size_t SLOT_B = (size_t)M_ROWS * D_MODEL * 2;
  bf16* u = (bf16*)(ws);
  bf16* wout16 = (bf16*)(ws);                    // u region, after conv
  bf16* yn = (bf16*)(ws + (2 << 20));            // u region +2MB
  bf16* y16 = (bf16*)(ws + (9 << 20));           // u region +9MB
  bf16* v = (bf16*)(ws + U_B);
  bf16* in16 = (bf16*)(ws + U_B + V_B);          // A
  bf16* k16 = in16;                              // A after GEMM1
  bf16* win16 = (bf16*)(ws + U_B + V_B + SLOT_B);// B
  bf16* q16 = win16;                             // B after GEMM1
  float* out = (float*)d_out;

  const int n4_in = M_ROWS * D_MODEL / 4;
  const int n4_win = INNER * D_MODEL / 4;
  const int n4_wout = D_MODEL * D_MODEL / 4;
  hipLaunchKernelGGL(cvt2_f32_bf16, dim3((n4_in + n4_win + 255) / 256),
                     dim3(256), 0, stream, inputs, in16, n4_in, w_in, win16,
                     n4_win);

  hipLaunchKernelGGL((gemm_bt<64, 128, INNER, false, bf16>), dim3(64, 18),
                     dim3(256), 0, stream, in16, win16, b_in,
                     (const float*)nullptr, u, 768);
  hipLaunchKernelGGL(conv_qkv, dim3(48, 2, 16), dim3(256), 0, stream, u, w_sf,
                     b_sf, q16, k16, v);
  // u dead now: stage w_out into its head
  hipLaunchKernelGGL(cvt_f32_bf16, dim3((n4_wout + 255) / 256), dim3(256), 0,
                     stream, w_out, wout16, n4_wout);
  hipLaunchKernelGGL(attn_kernel, dim3(48, 2, 32), dim3(256), 0, stream, q16,
                     k16, v, hb, y16);
  hipLaunchKernelGGL(rmsnorm_k, dim3(M_ROWS), dim3(256), 0, stream, y16,
                     norm_w, yn);
  hipLaunchKernelGGL((gemm_bt<64, 64, D_MODEL, true, float>), dim3(64, 12),
                     dim3(256), 0, stream, yn, wout16, b_out, inputs, out,
                     768);
}

// Round 14
// 188.280 us; speedup vs baseline: 1.1504x; 1.0078x over previous
//
#include <hip/hip_runtime.h>
#include <hip/hip_bf16.h>
#include <stdint.h>

typedef __bf16 bf16;
typedef __bf16 bf16x4 __attribute__((ext_vector_type(4)));
typedef __bf16 bf16x8 __attribute__((ext_vector_type(8)));
typedef float f32x4 __attribute__((ext_vector_type(4)));
typedef float f32x16 __attribute__((ext_vector_type(16)));

#define D_MODEL 768
#define NUM_HEADS 48
#define HEAD_CH 16
#define INNER 2304
#define BATCH 2
#define SEQLEN 2048
#define M_ROWS (BATCH * SEQLEN)
#define EPSF 1e-6f
// S-tile stride (bf16). MUST be 0 mod 8 (16B row alignment for ds_read_b128 —
// stride 36 broke this and cost +27us in r12). 40 = best aligned choice.
#define SST 40

// async global->LDS, 16B per lane. LDS dest must be wave-uniform base + lane*16.
__device__ inline void gload_lds16(const void* g, void* l) {
  __builtin_amdgcn_global_load_lds((__attribute__((address_space(1))) void*)(g),
                                   (__attribute__((address_space(3))) void*)(l),
                                   16, 0, 0);
}

// ---------------------------------------------------------------------------
// fused dual f32 -> bf16 convert (two independent tensors, one launch)
// ---------------------------------------------------------------------------
__global__ __launch_bounds__(256) void cvt2_f32_bf16(
    const float* __restrict__ a, bf16* __restrict__ da, int na4,
    const float* __restrict__ b, bf16* __restrict__ db, int nb4) {
  int j = blockIdx.x * 256 + threadIdx.x;
  const float* s;
  bf16* d;
  if (j < na4) {
    s = a; d = da;
  } else {
    j -= na4;
    if (j >= nb4) return;
    s = b; d = db;
  }
  const float4 v = ((const float4*)s)[j];
  bf16x4 o;
  o[0] = (bf16)v.x; o[1] = (bf16)v.y; o[2] = (bf16)v.z; o[3] = (bf16)v.w;
  ((bf16x4*)d)[j] = o;
}

__global__ __launch_bounds__(256) void cvt_f32_bf16(
    const float* __restrict__ src, bf16* __restrict__ dst, int n4) {
  const int i = blockIdx.x * 256 + threadIdx.x;
  if (i < n4) {
    const float4 v = ((const float4*)src)[i];
    bf16x4 o;
    o[0] = (bf16)v.x; o[1] = (bf16)v.y; o[2] = (bf16)v.z; o[3] = (bf16)v.w;
    ((bf16x4*)dst)[i] = o;
  }
}

// ---------------------------------------------------------------------------
// GEMM: C[m,n] = sum_k A[m,k]*W[n,k] + bias[n] (+ skip[m,n]); A (M,K), W (N,K)
// m97 pattern, TM x TN tile, BK in {32,64}. BK=64 stores two [kk0][row][32]
// sub-blocks -> DMA contiguity and 32-col fragment addressing preserved,
// barrier count halves (12 iters at K=768).
// ---------------------------------------------------------------------------
template <int TM, int TN, int BK, int NCOLS, bool ADD_SKIP, typename CT>
__global__ __launch_bounds__(256) void gemm_bt(
    const bf16* __restrict__ A, const bf16* __restrict__ W,
    const float* __restrict__ bias, const float* __restrict__ skip,
    CT* __restrict__ C, int K) {
  constexpr int MI = TM / 32;  // m-frags per wave
  constexpr int NI = TN / 32;  // n-frags per wave
  constexpr int KK = BK / 32;  // k sub-blocks
  __shared__ __align__(16) bf16 As[TM * BK];
  __shared__ __align__(16) bf16 Bs[TN * BK];
  const int t = threadIdx.x;
  const int lane = t & 63, w = t >> 6;
  const int wm = (w >> 1) * (TM / 2), wn = (w & 1) * (TN / 2);
  const int row16 = lane & 15, quad = lane >> 4;
  const int m0 = blockIdx.x * TM, n0 = blockIdx.y * TN;

  f32x4 zero4 = {0.f, 0.f, 0.f, 0.f};
  f32x4 acc[MI][NI];
#pragma unroll
  for (int mi = 0; mi < MI; ++mi)
#pragma unroll
    for (int ni = 0; ni < NI; ++ni) acc[mi][ni] = zero4;

  const int arow = t >> 2;        // 0..63
  const int acol = (t & 3) * 8;   // 0..24
  const bf16* Ab = A + (size_t)m0 * K;
  const bf16* Wb = W + (size_t)n0 * K;

  for (int kt = 0; kt < K; kt += BK) {
#pragma unroll
    for (int kk0 = 0; kk0 < KK; ++kk0) {
#pragma unroll
      for (int rh = 0; rh < TM / 64; ++rh)
        gload_lds16(Ab + (size_t)(rh * 64 + arow) * K + kt + kk0 * 32 + acol,
                    As + kk0 * (TM * 32) + rh * 2048 + t * 8);
#pragma unroll
      for (int rh = 0; rh < TN / 64; ++rh)
        gload_lds16(Wb + (size_t)(rh * 64 + arow) * K + kt + kk0 * 32 + acol,
                    Bs + kk0 * (TN * 32) + rh * 2048 + t * 8);
    }
    __syncthreads();

    bf16x8 af[MI][KK], wf[NI][KK];
#pragma unroll
    for (int kk0 = 0; kk0 < KK; ++kk0) {
#pragma unroll
      for (int mi = 0; mi < MI; ++mi)
        af[mi][kk0] = *(const bf16x8*)&As[kk0 * (TM * 32) +
                                          (wm + mi * 16 + row16) * 32 +
                                          quad * 8];
#pragma unroll
      for (int ni = 0; ni < NI; ++ni)
        wf[ni][kk0] = *(const bf16x8*)&Bs[kk0 * (TN * 32) +
                                          (wn + ni * 16 + row16) * 32 +
                                          quad * 8];
    }
#pragma unroll
    for (int kk0 = 0; kk0 < KK; ++kk0)
#pragma unroll
      for (int mi = 0; mi < MI; ++mi)
#pragma unroll
        for (int ni = 0; ni < NI; ++ni)
          acc[mi][ni] = __builtin_amdgcn_mfma_f32_16x16x32_bf16(
              af[mi][kk0], wf[ni][kk0], acc[mi][ni], 0, 0, 0);
    __syncthreads();
  }

#pragma unroll
  for (int mi = 0; mi < MI; ++mi) {
#pragma unroll
    for (int ni = 0; ni < NI; ++ni) {
      const int col = n0 + wn + ni * 16 + row16;
      const float bv = bias[col];
#pragma unroll
      for (int r = 0; r < 4; ++r) {
        const int row = m0 + wm + mi * 16 + quad * 4 + r;
        float v = acc[mi][ni][r] + bv;
        if (ADD_SKIP) v += skip[(size_t)row * NCOLS + col];
        C[(size_t)row * NCOLS + col] = (CT)v;
      }
    }
  }
}

// ---------------------------------------------------------------------------
// Q+K+V causal width-3 conv from u:
//   ch 0..15  -> Q (B,N,L,16);  16..31 -> K (B,N,L,16);  32..47 -> V (B,N,16,L)
// ---------------------------------------------------------------------------
__global__ __launch_bounds__(256) void conv_qkv(
    const bf16* __restrict__ u, const float* __restrict__ w_sf,
    const float* __restrict__ b_sf, bf16* __restrict__ qq,
    bf16* __restrict__ kk, bf16* __restrict__ vv) {
  const int nh = blockIdx.x, b = blockIdx.y, lc = blockIdx.z;
  const int l0 = lc * 128;
  __shared__ __align__(8) bf16 ut[130 * 48];
  const int t = threadIdx.x;
  for (int i = t; i < 130 * 12; i += 256) {
    const int lr = i / 12, qd = i % 12;
    const int l = l0 - 2 + lr;
    uint2 val;
    val.x = 0u; val.y = 0u;
    if (l >= 0)
      val = *(const uint2*)&u[(size_t)(b * SEQLEN + l) * INNER + nh * 48 + qd * 4];
    *(uint2*)&ut[lr * 48 + qd * 4] = val;
  }
  __syncthreads();
  const size_t bn = (size_t)(b * NUM_HEADS + nh);
#pragma unroll
  for (int s = 0; s < 2; ++s) {
    bf16* dst = (s == 0) ? qq : kk;
    const int cb = s * 16;
    for (int i = t; i < 128 * 16; i += 256) {
      const int c = i & 15, lr = i >> 4;
      const int e = nh * 48 + cb + c;
      const float val = w_sf[e * 3 + 0] * (float)ut[lr * 48 + cb + c] +
                        w_sf[e * 3 + 1] * (float)ut[(lr + 1) * 48 + cb + c] +
                        w_sf[e * 3 + 2] * (float)ut[(lr + 2) * 48 + cb + c] +
                        b_sf[e];
      dst[(bn * SEQLEN + l0 + lr) * 16 + c] = (bf16)val;
    }
  }
  for (int i = t; i < 128 * 16; i += 256) {
    const int lr = i & 127, c = i >> 7;
    const int e = nh * 48 + 32 + c;
    const float val = w_sf[e * 3 + 0] * (float)ut[lr * 48 + 32 + c] +
                      w_sf[e * 3 + 1] * (float)ut[(lr + 1) * 48 + 32 + c] +
                      w_sf[e * 3 + 2] * (float)ut[(lr + 2) * 48 + 32 + c] +
                      b_sf[e];
    vv[(bn * 16 + c) * SEQLEN + l0 + lr] = (bf16)val;
  }
}

// ---------------------------------------------------------------------------
// Causal h-weighted attention v10 (r13, frozen): balanced paired tiles.
// Block z owns tiles (z, 63-z); 65 combined KV chunks dealt round-robin to
// the 4 waves -> uniform duration. 3072 blocks. S^T = mfma_32x32x16(K,Q);
// zero-padded LDS h; S->A via LDS (stride 40); PV = 2x mfma_16x16x32.
// ---------------------------------------------------------------------------
__global__ __launch_bounds__(256) void attn_kernel(
    const bf16* __restrict__ qq, const bf16* __restrict__ kk,
    const bf16* __restrict__ vv, const float* __restrict__ hg,
    bf16* __restrict__ y) {
  const int nh = blockIdx.x, b = blockIdx.y;
  const int qa = blockIdx.z, qb = 63 - qa;  // paired tiles
  const int l0a = qa * 32, l0b = qb * 32;
  __shared__ __align__(16) float hs[32 + SEQLEN];  // hs[32+d]=h[d], pad=0
  __shared__ __align__(16) bf16 st[4 * 32 * SST];  // per-wave S-tile / O-redux
  const int t = threadIdx.x;
  const int n4 = (l0b + 64) >> 2;
  for (int i = t; i < n4; i += 256) {
    float4 val = {0.f, 0.f, 0.f, 0.f};
    if (i >= 8) val = ((const float4*)(hg + nh * SEQLEN))[i - 8];
    ((float4*)hs)[i] = val;
  }
  __syncthreads();

  const int w = t >> 6, lane = t & 63;
  const int l31 = lane & 31, hi = lane >> 5;
  const int row16 = lane & 15, quad = lane >> 4;
  const size_t bn = (size_t)(b * NUM_HEADS + nh);
  const bf16* qp = qq + bn * SEQLEN * 16;
  const bf16* kb = kk + bn * SEQLEN * 16;
  const bf16* vb = vv + bn * 16 * SEQLEN;

  bf16x8 zf;
#pragma unroll
  for (int j = 0; j < 8; ++j) zf[j] = (bf16)0.f;
  const f32x4 zacc4 = {0.f, 0.f, 0.f, 0.f};
  f32x16 zacc16;
#pragma unroll
  for (int j = 0; j < 16; ++j) zacc16[j] = 0.f;

  const bf16x8 qfa = *(const bf16x8*)&qp[(l0a + l31) * 16 + hi * 8];
  const bf16x8 qfb = *(const bf16x8*)&qp[(l0b + l31) * 16 + hi * 8];

  bf16* sw = &st[w * 32 * SST];

  auto run_pass = [&](const bf16x8& qf, const int l0, const int mc0,
                      f32x4& o0, f32x4& o1) {
    int mc = mc0;
    bf16x8 kf = zf, vf = zf;
    if (mc <= l0) {
      kf = *(const bf16x8*)&kb[(mc + l31) * 16 + hi * 8];
      vf = *(const bf16x8*)&vb[row16 * SEQLEN + mc + quad * 8];
    }
    for (; mc <= l0; mc += 128) {
      const int mn = mc + 128;
      bf16x8 kf2 = zf, vf2 = zf;
      if (mn <= l0) {  // prefetch next chunk
        kf2 = *(const bf16x8*)&kb[(mn + l31) * 16 + hi * 8];
        vf2 = *(const bf16x8*)&vb[row16 * SEQLEN + mn + quad * 8];
      }
      // S^T[m-local=rows][l-local=cols] = sum_ch K*Q
      f32x16 s =
          __builtin_amdgcn_mfma_f32_32x32x16_bf16(kf, qf, zacc16, 0, 0, 0);

      // h-weight; causal mask free via zero pad. reg j -> hp[3-j]
      const int d0 = 32 + (l0 - mc) + l31 - 4 * hi;
#pragma unroll
      for (int g = 0; g < 4; ++g) {
        const float* hp = &hs[d0 - 8 * g - 3];
        bf16x4 pk;
        pk[0] = (bf16)(s[4 * g + 0] * hp[3]);
        pk[1] = (bf16)(s[4 * g + 1] * hp[2]);
        pk[2] = (bf16)(s[4 * g + 2] * hp[1]);
        pk[3] = (bf16)(s[4 * g + 3] * hp[0]);
        *(bf16x4*)&sw[l31 * SST + 8 * g + 4 * hi] = pk;
      }
      asm volatile("s_waitcnt lgkmcnt(0)" ::: "memory");  // stores -> reads
      const bf16x8 sf0 = *(const bf16x8*)&sw[row16 * SST + quad * 8];
      const bf16x8 sf1 = *(const bf16x8*)&sw[(row16 + 16) * SST + quad * 8];
      o0 = __builtin_amdgcn_mfma_f32_16x16x32_bf16(sf0, vf, o0, 0, 0, 0);
      o1 = __builtin_amdgcn_mfma_f32_16x16x32_bf16(sf1, vf, o1, 0, 0, 0);
      asm volatile("" ::: "memory");  // reads before next-iter stores
      kf = kf2; vf = vf2;
    }
  };

  f32x4 o0a = zacc4, o1a = zacc4, o0b = zacc4, o1b = zacc4;
  run_pass(qfa, l0a, w * 32, o0a, o1a);
  const int j0 = ((w - qa - 1) % 4 + 4) % 4;
  run_pass(qfb, l0b, j0 * 32, o0b, o1b);

  // epilogue: two phases reusing st as 4 x (32x16 f32) reduction buffers
  float* ob = (float*)&st[w * 32 * SST];
#pragma unroll
  for (int phase = 0; phase < 2; ++phase) {
    const f32x4& p0 = phase ? o0b : o0a;
    const f32x4& p1 = phase ? o1b : o1a;
    const int lt = phase ? l0b : l0a;
    __syncthreads();
#pragma unroll
    for (int r = 0; r < 4; ++r) {
      ob[(quad * 4 + r) * 16 + row16] = p0[r];
      ob[(quad * 4 + r + 16) * 16 + row16] = p1[r];
    }
    __syncthreads();
    for (int i = t; i < 32 * 16; i += 256) {
      const int l = i >> 4, j = i & 15;
      float sum = 0.f;
#pragma unroll
      for (int ww = 0; ww < 4; ++ww)
        sum += ((const float*)&st[ww * 32 * SST])[l * 16 + j];
      y[((size_t)(b * SEQLEN + lt + l) * NUM_HEADS + nh) * 16 + j] = (bf16)sum;
    }
  }
}

// ---------------------------------------------------------------------------
// RMSNorm over D=768 per row: y bf16 in, yn bf16 out, * norm_w (f32)
// ---------------------------------------------------------------------------
__global__ __launch_bounds__(256) void rmsnorm_k(
    const bf16* __restrict__ y, const float* __restrict__ nw,
    bf16* __restrict__ yn) {
  const int row = blockIdx.x;
  const int t = threadIdx.x;
  const bf16* yr = y + (size_t)row * D_MODEL;
  const float v0 = (float)yr[t];
  const float v1 = (float)yr[t + 256];
  const float v2 = (float)yr[t + 512];
  float ss = v0 * v0 + v1 * v1 + v2 * v2;
#pragma unroll
  for (int off = 32; off >= 1; off >>= 1) ss += __shfl_down(ss, off, 64);
  __shared__ float red[4];
  if ((t & 63) == 0) red[t >> 6] = ss;
  __syncthreads();
  const float tot = red[0] + red[1] + red[2] + red[3];
  const float r = rsqrtf(tot * (1.f / 768.f) + EPSF);
  bf16* yo = yn + (size_t)row * D_MODEL;
  yo[t] = (bf16)(v0 * r * nw[t]);
  yo[t + 256] = (bf16)(v1 * r * nw[t + 256]);
  yo[t + 512] = (bf16)(v2 * r * nw[t + 512]);
}

// ---------------------------------------------------------------------------
extern "C" void kernel_launch(void* const* d_in, const int* in_sizes, int n_in,
                              void* d_out, int out_size, void* d_ws,
                              size_t ws_size, hipStream_t stream) {
  const float* inputs = (const float*)d_in[0];
  const float* w_in = (const float*)d_in[1];
  const float* b_in = (const float*)d_in[2];
  const float* w_sf = (const float*)d_in[3];
  const float* b_sf = (const float*)d_in[4];
  const float* hb = (const float*)d_in[5];
  const float* norm_w = (const float*)d_in[6];
  const float* w_out = (const float*)d_in[7];
  const float* b_out = (const float*)d_in[8];

  // ws plan (37.8 MB), region lifetimes:
  //   u   18.9 MB : GEMM1 out -> dead after conv_qkv; tail reused for
  //                 wout16 (+0, 1.2MB), yn (+2MB, 6.3MB), y16 (+9MB, 6.3MB)
  //   v    6.3 MB : V
  //   A    6.3 MB : in16 (GEMM1 A) -> k16 (attn) -> dead
  //   B    6.3 MB : win16 (GEMM1 W, 3.5MB) -> q16 (attn)
  char* ws = (char*)d_ws;
  const size_t U_B = (size_t)M_ROWS * INNER * 2;
  const size_t V_B = (size_t)BATCH * NUM_HEADS * HEAD_CH * SEQLEN * 2;
  const size_t SLOT_B = (size_t)M_ROWS * D_MODEL * 2;
  bf16* u = (bf16*)(ws);
  bf16* wout16 = (bf16*)(ws);                    // u region, after conv
  bf16* yn = (bf16*)(ws + (2 << 20));            // u region +2MB
  bf16* y16 = (bf16*)(ws + (9 << 20));           // u region +9MB
  bf16* v = (bf16*)(ws + U_B);
  bf16* in16 = (bf16*)(ws + U_B + V_B);          // A
  bf16* k16 = in16;                              // A after GEMM1
  bf16* win16 = (bf16*)(ws + U_B + V_B + SLOT_B);// B
  bf16* q16 = win16;                             // B after GEMM1
  float* out = (float*)d_out;

  const int n4_in = M_ROWS * D_MODEL / 4;
  const int n4_win = INNER * D_MODEL / 4;
  const int n4_wout = D_MODEL * D_MODEL / 4;
  hipLaunchKernelGGL(cvt2_f32_bf16, dim3((n4_in + n4_win + 255) / 256),
                     dim3(256), 0, stream, inputs, in16, n4_in, w_in, win16,
                     n4_win);

  hipLaunchKernelGGL((gemm_bt<64, 128, 64, INNER, false, bf16>), dim3(64, 18),
                     dim3(256), 0, stream, in16, win16, b_in,
                     (const float*)nullptr, u, 768);
  hipLaunchKernelGGL(conv_qkv, dim3(48, 2, 16), dim3(256), 0, stream, u, w_sf,
                     b_sf, q16, k16, v);
  // u dead now: stage w_out into its head
  hipLaunchKernelGGL(cvt_f32_bf16, dim3((n4_wout + 255) / 256), dim3(256), 0,
                     stream, w_out, wout16, n4_wout);
  hipLaunchKernelGGL(attn_kernel, dim3(48, 2, 32), dim3(256), 0, stream, q16,
                     k16, v, hb, y16);
  hipLaunchKernelGGL(rmsnorm_k, dim3(M_ROWS), dim3(256), 0, stream, y16,
                     norm_w, yn);
  hipLaunchKernelGGL((gemm_bt<64, 64, 64, D_MODEL, true, float>), dim3(64, 12),
                     dim3(256), 0, stream, yn, wout16, b_out, inputs, out,
                     768);
}